// Round 2
// baseline (1042.984 us; speedup 1.0000x reference)
//
#include <hip/hip_runtime.h>
#include <hip/hip_bf16.h>

// Problem constants (from reference): N=32768 queries, D=256 dims, K=4096 codes.
#define VQ_N 32768
#define VQ_D 256
#define VQ_K 4096

// ---------------------------------------------------------------------------
// Kernel 1: codebook squared norms c2[k] = sum_d cb[k][d]^2
// One wave per code; lane reads float4 (64 lanes * 4 = 256 = D).
// ---------------------------------------------------------------------------
__global__ void c2_kernel(const float* __restrict__ cb, float* __restrict__ c2) {
    const int wave = threadIdx.x >> 6;
    const int lane = threadIdx.x & 63;
    const int code = blockIdx.x * 4 + wave;
    const float4 v = *reinterpret_cast<const float4*>(&cb[(size_t)code * VQ_D + lane * 4]);
    float s = v.x * v.x + v.y * v.y + v.z * v.z + v.w * v.w;
    #pragma unroll
    for (int off = 32; off > 0; off >>= 1) s += __shfl_xor(s, off, 64);
    if (lane == 0) c2[code] = s;
}

// ---------------------------------------------------------------------------
// Kernel 2: fused distance GEMM + argmin.
// Block tile: 128 rows (x) x 128 codes, looped over 8 code-tiles (1024 codes
// per block via gridDim.y=4 K-split). Inner D staged in d-major LDS chunks of
// 32 so fragment reads are ds_read_b128, conflict-free (A: broadcast; B: 4-way
// worst case). Per-thread 8x8 fp32 accumulator -> 64 FMAs per 4 LDS reads.
// argmin uses key ordering identical to jnp.argmin on d2 = x2 + c2 - 2 x.c
// (x2 is a per-row constant -> omitted; clamp-at-0 cannot activate for
// Gaussian data where min d2 ~ hundreds).
// ---------------------------------------------------------------------------
__global__ __launch_bounds__(256, 2)
void vq_argmin_kernel(const float* __restrict__ x, const float* __restrict__ cb,
                      const float* __restrict__ c2,
                      unsigned long long* __restrict__ keys) {
    const int t  = threadIdx.x;
    const int tx = t & 15;   // code-group index
    const int ty = t >> 4;   // row-group index (0..15)
    const int rowbase = blockIdx.x * 128;
    const int cstart  = blockIdx.y * 1024;

    __shared__ float xs[32 * 128];  // [d][row] d-major
    __shared__ float cs[32 * 128];  // [d][code] d-major

    float runv[8];
    int   runc[8];
    #pragma unroll
    for (int i = 0; i < 8; ++i) { runv[i] = 3.4e38f; runc[i] = 0x7fffffff; }

    for (int ct = 0; ct < 8; ++ct) {
        const int cbase = cstart + ct * 128;
        float acc[8][8];
        #pragma unroll
        for (int i = 0; i < 8; ++i)
            #pragma unroll
            for (int j = 0; j < 8; ++j) acc[i][j] = 0.0f;

        for (int dc = 0; dc < 8; ++dc) {   // 8 chunks of 32 dims = 256
            const int d0 = dc * 32;
            __syncthreads();               // protect LDS from previous readers
            // Stage 32x128 of x and cb, transposing to d-major.
            // idx -> col (row/code within tile) = idx & 127, dq = idx >> 7.
            #pragma unroll
            for (int it = 0; it < 4; ++it) {
                const int idx = t + 256 * it;          // 0..1023 float4s
                const int col = idx & 127;
                const int dq  = idx >> 7;              // 0..7
                const float4 xv = *reinterpret_cast<const float4*>(
                    &x[(size_t)(rowbase + col) * VQ_D + d0 + dq * 4]);
                const float4 cv = *reinterpret_cast<const float4*>(
                    &cb[(size_t)(cbase + col) * VQ_D + d0 + dq * 4]);
                xs[(dq * 4 + 0) * 128 + col] = xv.x;
                xs[(dq * 4 + 1) * 128 + col] = xv.y;
                xs[(dq * 4 + 2) * 128 + col] = xv.z;
                xs[(dq * 4 + 3) * 128 + col] = xv.w;
                cs[(dq * 4 + 0) * 128 + col] = cv.x;
                cs[(dq * 4 + 1) * 128 + col] = cv.y;
                cs[(dq * 4 + 2) * 128 + col] = cv.z;
                cs[(dq * 4 + 3) * 128 + col] = cv.w;
            }
            __syncthreads();

            #pragma unroll 4
            for (int d = 0; d < 32; ++d) {
                const float4 a0 = *reinterpret_cast<const float4*>(&xs[d * 128 + ty * 8]);
                const float4 a1 = *reinterpret_cast<const float4*>(&xs[d * 128 + ty * 8 + 4]);
                const float4 b0 = *reinterpret_cast<const float4*>(&cs[d * 128 + tx * 8]);
                const float4 b1 = *reinterpret_cast<const float4*>(&cs[d * 128 + tx * 8 + 4]);
                const float a[8] = {a0.x, a0.y, a0.z, a0.w, a1.x, a1.y, a1.z, a1.w};
                const float b[8] = {b0.x, b0.y, b0.z, b0.w, b1.x, b1.y, b1.z, b1.w};
                #pragma unroll
                for (int i = 0; i < 8; ++i)
                    #pragma unroll
                    for (int j = 0; j < 8; ++j)
                        acc[i][j] = fmaf(a[i], b[j], acc[i][j]);
            }
        }

        // Tile epilogue: form score = c2 - 2*dot, reduce argmin over this tile.
        const float4 c2a = *reinterpret_cast<const float4*>(&c2[cbase + tx * 8]);
        const float4 c2b = *reinterpret_cast<const float4*>(&c2[cbase + tx * 8 + 4]);
        const float cc[8] = {c2a.x, c2a.y, c2a.z, c2a.w, c2b.x, c2b.y, c2b.z, c2b.w};
        #pragma unroll
        for (int i = 0; i < 8; ++i) {
            float bv = 3.4e38f;
            int   bc = 0x7fffffff;
            #pragma unroll
            for (int j = 0; j < 8; ++j) {
                const float v = cc[j] - 2.0f * acc[i][j];
                const int code = cbase + tx * 8 + j;
                if (v < bv) { bv = v; bc = code; }       // ascending j: ties keep lower idx
            }
            // reduce across the 16 tx lanes (contiguous lanes in the wave)
            #pragma unroll
            for (int off = 1; off < 16; off <<= 1) {
                const float ov = __shfl_xor(bv, off, 64);
                const int   oc = __shfl_xor(bc, off, 64);
                if (ov < bv || (ov == bv && oc < bc)) { bv = ov; bc = oc; }
            }
            if (bv < runv[i]) { runv[i] = bv; runc[i] = bc; }  // ct ascending: strict < == first-min
        }
    }

    if (tx == 0) {
        #pragma unroll
        for (int i = 0; i < 8; ++i) {
            const int row = rowbase + ty * 8 + i;
            const unsigned int b = __float_as_uint(runv[i]);
            // monotone float->uint map (handles negative scores)
            const unsigned int u = (b & 0x80000000u) ? ~b : (b | 0x80000000u);
            const unsigned long long key =
                ((unsigned long long)u << 32) | (unsigned int)runc[i];
            atomicMin(&keys[row], key);
        }
    }
}

// ---------------------------------------------------------------------------
// Kernel 3: finalize. One wave per row: unpack key -> ind, gather codebook row
// to out (exact fp32 copy == straight-through forward), accumulate commitment
// loss partial sums.
// ---------------------------------------------------------------------------
__global__ void finalize_kernel(const float* __restrict__ x, const float* __restrict__ cb,
                                const unsigned long long* __restrict__ keys,
                                float* __restrict__ out, float* __restrict__ ind_out,
                                float* __restrict__ loss_accum) {
    const int wave = threadIdx.x >> 6;
    const int lane = threadIdx.x & 63;
    const int row  = blockIdx.x * 4 + wave;
    const unsigned long long key = keys[row];
    const int code = (int)(key & 0xFFFFFFFFull);

    const float4 q  = *reinterpret_cast<const float4*>(&cb[(size_t)code * VQ_D + lane * 4]);
    const float4 xv = *reinterpret_cast<const float4*>(&x[(size_t)row * VQ_D + lane * 4]);
    *reinterpret_cast<float4*>(&out[(size_t)row * VQ_D + lane * 4]) = q;
    if (lane == 0) ind_out[row] = (float)code;

    const float dx = q.x - xv.x, dy = q.y - xv.y, dz = q.z - xv.z, dw = q.w - xv.w;
    float s = dx * dx + dy * dy + dz * dz + dw * dw;
    #pragma unroll
    for (int off = 32; off > 0; off >>= 1) s += __shfl_xor(s, off, 64);

    __shared__ float ls[4];
    if (lane == 0) ls[wave] = s;
    __syncthreads();
    if (threadIdx.x == 0) atomicAdd(loss_accum, ls[0] + ls[1] + ls[2] + ls[3]);
}

__global__ void scale_kernel(const float* __restrict__ loss_accum,
                             float* __restrict__ loss_out) {
    *loss_out = loss_accum[0] * (1.0f / ((float)VQ_N * (float)VQ_D));
}

// ---------------------------------------------------------------------------
// Launch: d_out layout = [out (N*D) | ind as float (N) | commit_loss (1)].
// Workspace: c2 (K floats) | keys (N u64) | loss accumulator (1 float).
// ---------------------------------------------------------------------------
extern "C" void kernel_launch(void* const* d_in, const int* in_sizes, int n_in,
                              void* d_out, int out_size, void* d_ws, size_t ws_size,
                              hipStream_t stream) {
    const float* x  = (const float*)d_in[0];
    const float* cb = (const float*)d_in[1];
    float* out = (float*)d_out;
    float* ind_out  = out + (size_t)VQ_N * VQ_D;
    float* loss_out = out + (size_t)VQ_N * VQ_D + VQ_N;

    float* c2 = (float*)d_ws;                                     // 16 KB
    unsigned long long* keys =
        (unsigned long long*)((char*)d_ws + VQ_K * sizeof(float)); // 256 KB
    float* loss_accum = (float*)((char*)d_ws + VQ_K * sizeof(float)
                                 + (size_t)VQ_N * sizeof(unsigned long long));

    hipMemsetAsync(keys, 0xFF, (size_t)VQ_N * sizeof(unsigned long long), stream);
    hipMemsetAsync(loss_accum, 0, sizeof(float), stream);

    c2_kernel<<<VQ_K / 4, 256, 0, stream>>>(cb, c2);

    dim3 grid2(VQ_N / 128, 4);   // 4-way K split -> 1024 blocks
    vq_argmin_kernel<<<grid2, 256, 0, stream>>>(x, cb, c2, keys);

    finalize_kernel<<<VQ_N / 4, 256, 0, stream>>>(x, cb, keys, out, ind_out, loss_accum);
    scale_kernel<<<1, 1, 0, stream>>>(loss_accum, loss_out);
}